// Round 5
// baseline (376.336 us; speedup 1.0000x reference)
//
#include <hip/hip_runtime.h>
#include <hip/hip_cooperative_groups.h>

namespace cg = cooperative_groups;

#define BB   8
#define CC   64
#define HWN  19200
#define NPTS 12800
#define NSUB 3200
#define KNN  16
#define OUTN (HWN + NSUB)   // 22400

typedef __attribute__((ext_vector_type(8))) short short8;
typedef __attribute__((ext_vector_type(4))) float floatx4;

__device__ __forceinline__ unsigned short f2bf(float f) {
    union { float f; unsigned int i; } v; v.f = f;
    unsigned int r = v.i + 0x7fffu + ((v.i >> 16) & 1u);
    return (unsigned short)(r >> 16);
}
__device__ __forceinline__ float bf2f(unsigned short u) {
    union { unsigned int i; float f; } v; v.i = ((unsigned int)u) << 16; return v.f;
}

struct P {
    const float* pfeat; const float* rgb;
    const float* w0; const float* w1; const float* w2; const float* w3;
    const float* s_pp; const float* b_pp;
    const float* s_rp; const float* b_rp;
    const float* s_pf; const float* b_pf;
    const float* s_rf; const float* b_rf;
    const int* pool_idx; const int* p2r_idx; const int* r2p_idx;
    ushort* wB; ushort* pfT; ushort* rgbT;
    ushort* pe0T; ushort* p2rT; ushort* r2pT;
    float* out;
    int grid;
};

// ---------------- phase bodies (shared by coop kernel and fallback kernels) ----

__device__ __forceinline__ void phase1_item(const P& p, int w, int tid, ushort* sm) {
    if (w >= 4000) {             // weight cvt: 96 items x 256 = 24576 elems
        int i = (w - 4000) * 256 + tid;
        float v;
        if (i < 4096)       v = p.w0[i];
        else if (i < 8192)  v = p.w1[i - 4096];
        else if (i < 16384) v = p.w2[i - 8192];
        else                v = p.w3[i - 16384];
        p.wB[i] = f2bf(v);
        return;
    }
    bool isR = (w >= 1600);
    int v0 = isR ? w - 1600 : w;
    int b = v0 & 7, xx = v0 >> 3;
    const float* in = isR ? p.rgb : p.pfeat;
    ushort* outp    = isR ? p.rgbT : p.pfT;
    int N  = isR ? HWN : NPTS;
    int n0 = xx * 64;
    int tx = tid & 63, ty = tid >> 6;
    __syncthreads();             // protect LDS reuse across grid-stride iterations
    const float* src = in + (size_t)b * CC * N + n0;
    #pragma unroll
    for (int c = ty; c < CC; c += 4)
        sm[c * 65 + tx] = f2bf(src[(size_t)c * N + tx]);
    __syncthreads();
    ushort* dst = outp + ((size_t)b * N + n0) * CC;
    #pragma unroll
    for (int n = ty; n < 64; n += 4)
        dst[(size_t)n * CC + tx] = sm[tx * 65 + n];
}

__device__ __forceinline__ void phase2_item(const P& p, int w, int tid, ushort* sm) {
    bool pt = (w < 400);
    int v0 = pt ? w : w - 400;
    int b = v0 & 7, xx = v0 >> 3;     // xx 0..49
    int m0 = xx * 64;
    const ushort* xT  = pt ? p.pfT : p.rgbT;
    const int*    idx = pt ? p.pool_idx : p.r2p_idx;
    int Nin           = pt ? NPTS : HWN;
    const ushort* W   = pt ? p.wB : p.wB + 4096;   // [64][64]
    const float*  sv  = pt ? p.s_pp : p.s_rp;
    const float*  bv  = pt ? p.b_pp : p.b_rp;
    ushort*       dst = pt ? p.p2rT : p.r2pT;

    __syncthreads();
    int c4   = (tid & 15) * 4;
    int mloc = tid >> 4;
    const ushort* xb = xT + (size_t)b * Nin * CC + c4;
    #pragma unroll
    for (int pass = 0; pass < 4; ++pass) {
        int ml = mloc + pass * 16;
        int m  = m0 + ml;
        const int* ip = idx + ((size_t)b * NSUB + m) * KNN;
        float a0 = -1e30f, a1 = -1e30f, a2 = -1e30f, a3 = -1e30f;
        #pragma unroll
        for (int k = 0; k < KNN; ++k) {
            int j = ip[k];
            ushort4 v = *(const ushort4*)(xb + (size_t)j * CC);
            a0 = fmaxf(a0, bf2f(v.x));
            a1 = fmaxf(a1, bf2f(v.y));
            a2 = fmaxf(a2, bf2f(v.z));
            a3 = fmaxf(a3, bf2f(v.w));
        }
        ushort4 r;
        r.x = f2bf(a0); r.y = f2bf(a1); r.z = f2bf(a2); r.w = f2bf(a3);
        *(ushort4*)(&sm[ml * 72 + c4]) = r;
        if (pt)
            *(ushort4*)(p.pe0T + ((size_t)b * NSUB + m) * CC + c4) = r;
    }
    __syncthreads();
    int wave = tid >> 6, lane = tid & 63;
    int l15 = lane & 15, quad = lane >> 4;
    int nloc0 = wave * 16;
    floatx4 acc[4] = {{0.f,0.f,0.f,0.f},{0.f,0.f,0.f,0.f},{0.f,0.f,0.f,0.f},{0.f,0.f,0.f,0.f}};
    #pragma unroll
    for (int kk = 0; kk < 2; ++kk) {
        short8 a = *(const short8*)(&sm[(nloc0 + l15) * 72 + kk * 32 + quad * 8]);
        #pragma unroll
        for (int t = 0; t < 4; ++t) {
            short8 wf = *(const short8*)(W + (size_t)(t * 16 + l15) * CC + kk * 32 + quad * 8);
            acc[t] = __builtin_amdgcn_mfma_f32_16x16x32_bf16(a, wf, acc[t], 0, 0, 0);
        }
    }
    #pragma unroll
    for (int t = 0; t < 4; ++t) {
        int o = t * 16 + l15;
        float ss = sv[o], bb2 = bv[o];
        #pragma unroll
        for (int r = 0; r < 4; ++r) {
            int n = m0 + nloc0 + quad * 4 + r;
            float y = fmaxf(acc[t][r] * ss + bb2, 0.f);
            dst[((size_t)b * NSUB + n) * CC + o] = f2bf(y);
        }
    }
}

__device__ __forceinline__ void phase3_item(const P& p, int w, int tid) {
    bool rp = (w < 2400);
    int v0 = rp ? w : w - 2400;
    int b = v0 & 7, x0 = v0 >> 3;     // 0..299 / 0..49
    const ushort* x1T = rp ? p.rgbT : p.pe0T;
    const ushort* x2T = rp ? p.p2rT : p.r2pT;
    int N             = rp ? HWN : NSUB;
    int pos0          = rp ? 0 : HWN;
    const ushort* W   = rp ? p.wB + 8192 : p.wB + 16384;   // [64][128]
    const float*  sv  = rp ? p.s_pf : p.s_rf;
    const float*  bv  = rp ? p.b_pf : p.b_rf;

    int wave = tid >> 6, lane = tid & 63;
    int n0 = (x0 * 4 + wave) * 16;
    int l15 = lane & 15, quad = lane >> 4;
    int n  = n0 + l15;
    int n2 = rp ? p.p2r_idx[(size_t)b * N + n] : n;
    const ushort* r1 = x1T + ((size_t)b * N + n) * CC + quad * 8;
    const ushort* r2 = x2T + ((size_t)b * NSUB + n2) * CC + quad * 8;
    floatx4 acc[4] = {{0.f,0.f,0.f,0.f},{0.f,0.f,0.f,0.f},{0.f,0.f,0.f,0.f},{0.f,0.f,0.f,0.f}};
    #pragma unroll
    for (int kk = 0; kk < 4; ++kk) {
        short8 xb = (kk < 2) ? *(const short8*)(r1 + kk * 32)
                             : *(const short8*)(r2 + (kk - 2) * 32);
        #pragma unroll
        for (int t = 0; t < 4; ++t) {
            short8 wf = *(const short8*)(W + (size_t)(t * 16 + l15) * 128 + kk * 32 + quad * 8);
            acc[t] = __builtin_amdgcn_mfma_f32_16x16x32_bf16(wf, xb, acc[t], 0, 0, 0);
        }
    }
    #pragma unroll
    for (int t = 0; t < 4; ++t) {
        #pragma unroll
        for (int r = 0; r < 4; ++r) {
            int o = t * 16 + quad * 4 + r;
            float y = fmaxf(acc[t][r] * sv[o] + bv[o], 0.f);
            p.out[((size_t)b * CC + o) * OUTN + pos0 + n] = y;
        }
    }
}

// ---------------- cooperative all-in-one ----------------
__global__ __launch_bounds__(256, 2) void k_all(P p) {
    __shared__ ushort sm[64 * 72];
    cg::grid_group grid = cg::this_grid();
    int tid = threadIdx.x;
    for (int w = blockIdx.x; w < 4096; w += p.grid) phase1_item(p, w, tid, sm);
    grid.sync();
    for (int w = blockIdx.x; w < 800;  w += p.grid) phase2_item(p, w, tid, sm);
    grid.sync();
    for (int w = blockIdx.x; w < 2800; w += p.grid) phase3_item(p, w, tid);
}

// ---------------- fallback: three separate kernels (round-3 proven) ----------
__global__ __launch_bounds__(256) void k_p1(P p) {
    __shared__ ushort sm[64 * 72];
    for (int w = blockIdx.x; w < 4096; w += p.grid) phase1_item(p, w, threadIdx.x, sm);
}
__global__ __launch_bounds__(256) void k_p2(P p) {
    __shared__ ushort sm[64 * 72];
    for (int w = blockIdx.x; w < 800; w += p.grid) phase2_item(p, w, threadIdx.x, sm);
}
__global__ __launch_bounds__(256) void k_p3(P p) {
    for (int w = blockIdx.x; w < 2800; w += p.grid) phase3_item(p, w, threadIdx.x);
}

extern "C" void kernel_launch(void* const* d_in, const int* in_sizes, int n_in,
                              void* d_out, int out_size, void* d_ws, size_t ws_size,
                              hipStream_t stream) {
    char* ws = (char*)d_ws;
    ushort* wB   = (ushort*)ws; ws += 24576 * 2;
    ushort* pfT  = (ushort*)ws; ws += (size_t)BB * NPTS * CC * 2;
    ushort* rgbT = (ushort*)ws; ws += (size_t)BB * HWN  * CC * 2;
    ushort* pe0T = (ushort*)ws; ws += (size_t)BB * NSUB * CC * 2;
    ushort* p2rT = (ushort*)ws; ws += (size_t)BB * NSUB * CC * 2;
    ushort* r2pT = (ushort*)ws; ws += (size_t)BB * NSUB * CC * 2;

    P p;
    p.pfeat = (const float*)d_in[1];
    p.rgb   = (const float*)d_in[0];
    p.w0    = (const float*)d_in[2];
    p.w1    = (const float*)d_in[8];
    p.w2    = (const float*)d_in[5];
    p.w3    = (const float*)d_in[11];
    p.s_pp  = (const float*)d_in[3];   p.b_pp = (const float*)d_in[4];
    p.s_rp  = (const float*)d_in[9];   p.b_rp = (const float*)d_in[10];
    p.s_pf  = (const float*)d_in[6];   p.b_pf = (const float*)d_in[7];
    p.s_rf  = (const float*)d_in[12];  p.b_rf = (const float*)d_in[13];
    p.pool_idx = (const int*)d_in[14];
    p.p2r_idx  = (const int*)d_in[15];
    p.r2p_idx  = (const int*)d_in[16];
    p.wB = wB; p.pfT = pfT; p.rgbT = rgbT;
    p.pe0T = pe0T; p.p2rT = p2rT; p.r2pT = r2pT;
    p.out = (float*)d_out;

    // Size the cooperative grid from the SAME occupancy number the launch
    // validator uses, so hipErrorCooperativeLaunchTooLarge cannot recur.
    int maxB = 0;
    hipError_t qe = hipOccupancyMaxActiveBlocksPerMultiprocessor(
        &maxB, reinterpret_cast<const void*>(k_all), 256, 0);
    bool done = false;
    if (qe == hipSuccess && maxB >= 1) {
        int grid = maxB * 256;           // 256 CUs
        if (grid > 1024) grid = 1024;    // enough blocks; more adds no parallelism
        p.grid = grid;
        void* args[] = { &p };
        hipError_t le = hipLaunchCooperativeKernel(
            reinterpret_cast<const void*>(k_all), dim3(grid), dim3(256), args, 0, stream);
        if (le == hipSuccess) done = true;
        else (void)hipGetLastError();    // clear error state before fallback
    } else {
        (void)hipGetLastError();
    }

    if (!done) {  // proven round-3 path
        p.grid = 1024;
        k_p1<<<dim3(1024), 256, 0, stream>>>(p);
        p.grid = 800;
        k_p2<<<dim3(800), 256, 0, stream>>>(p);
        p.grid = 1024;
        k_p3<<<dim3(1024), 256, 0, stream>>>(p);
    }
}

// Round 6
// 195.836 us; speedup vs baseline: 1.9217x; 1.9217x over previous
//
#include <hip/hip_runtime.h>

#define BB   8
#define CC   64
#define HWN  19200
#define NPTS 12800
#define NSUB 3200
#define KNN  16
#define OUTN (HWN + NSUB)   // 22400

typedef __attribute__((ext_vector_type(8))) short short8;
typedef __attribute__((ext_vector_type(4))) float floatx4;

__device__ __forceinline__ unsigned short f2bf(float f) {
    union { float f; unsigned int i; } v; v.f = f;
    unsigned int r = v.i + 0x7fffu + ((v.i >> 16) & 1u);
    return (unsigned short)(r >> 16);
}
__device__ __forceinline__ float bf2f(unsigned short u) {
    union { unsigned int i; float f; } v; v.i = ((unsigned int)u) << 16; return v.f;
}

struct P {
    const float* pfeat; const float* rgb;
    const float* w0; const float* w1; const float* w2; const float* w3;
    const float* s_pp; const float* b_pp;
    const float* s_rp; const float* b_rp;
    const float* s_pf; const float* b_pf;
    const float* s_rf; const float* b_rf;
    const int* pool_idx; const int* p2r_idx; const int* r2p_idx;
    ushort* wB; ushort* pfT; ushort* rgbT;
    ushort* pe0T; ushort* p2rT; ushort* r2pT;
    float* out;
};

// ---------------------------------------------------------------------------
// K1: transposes f32 [B][C][N] -> bf16 [B][N][C] (vectorized: float4 in,
// ushort4 out) + weight conversion. grid 4096: w<1600 pfeat, <4000 rgb,
// >=4000 weights.
// ---------------------------------------------------------------------------
__global__ __launch_bounds__(256) void k_p1(P p) {
    __shared__ ushort sm[64 * 65];
    int w = blockIdx.x, tid = threadIdx.x;
    if (w >= 4000) {              // weight cvt: 96 blocks x 256 = 24576 elems
        int i = (w - 4000) * 256 + tid;
        float v;
        if (i < 4096)       v = p.w0[i];
        else if (i < 8192)  v = p.w1[i - 4096];
        else if (i < 16384) v = p.w2[i - 8192];
        else                v = p.w3[i - 16384];
        p.wB[i] = f2bf(v);
        return;
    }
    bool isR = (w >= 1600);
    int v0 = isR ? w - 1600 : w;
    int b = v0 & 7, xx = v0 >> 3;
    const float* src = (isR ? p.rgb : p.pfeat);
    ushort* outp     = (isR ? p.rgbT : p.pfT);
    int N  = isR ? HWN : NPTS;
    int n0 = xx * 64;
    src += (size_t)b * CC * N + n0;

    // load: 16 lanes x float4 per c-row; 16 c-rows per pass, 4 passes
    int l = tid & 15, ch = tid >> 4;
    #pragma unroll
    for (int it = 0; it < 4; ++it) {
        int c = ch + 16 * it;
        float4 v = *(const float4*)(src + (size_t)c * N + 4 * l);
        sm[c * 65 + 4 * l + 0] = f2bf(v.x);
        sm[c * 65 + 4 * l + 1] = f2bf(v.y);
        sm[c * 65 + 4 * l + 2] = f2bf(v.z);
        sm[c * 65 + 4 * l + 3] = f2bf(v.w);
    }
    __syncthreads();
    // store: lane writes ushort4 (4 channels) of one n-row; 512B/wave/instr
    ushort* dst = outp + ((size_t)b * N + n0) * CC;
    int c4 = (tid & 15) * 4;
    #pragma unroll
    for (int it = 0; it < 4; ++it) {
        int n = (tid >> 4) + 16 * it;
        ushort4 r;
        r.x = sm[(c4 + 0) * 65 + n];
        r.y = sm[(c4 + 1) * 65 + n];
        r.z = sm[(c4 + 2) * 65 + n];
        r.w = sm[(c4 + 3) * 65 + n];
        *(ushort4*)(dst + (size_t)n * CC + c4) = r;
    }
}

// ---------------------------------------------------------------------------
// K2: gather + maxpool + pre-conv GEMM. grid 800: w<400 point-stream,
// else rgb-stream. One block = 64 points.
// ---------------------------------------------------------------------------
__global__ __launch_bounds__(256) void k_p2(P p) {
    __shared__ ushort sm[64 * 72];
    int w = blockIdx.x, tid = threadIdx.x;
    bool pt = (w < 400);
    int v0 = pt ? w : w - 400;
    int b = v0 & 7, xx = v0 >> 3;     // xx 0..49
    int m0 = xx * 64;
    const ushort* xT  = pt ? p.pfT : p.rgbT;
    const int*    idx = pt ? p.pool_idx : p.r2p_idx;
    int Nin           = pt ? NPTS : HWN;
    const ushort* W   = pt ? p.wB : p.wB + 4096;   // [64][64]
    const float*  sv  = pt ? p.s_pp : p.s_rp;
    const float*  bv  = pt ? p.b_pp : p.b_rp;
    ushort*       dst = pt ? p.p2rT : p.r2pT;

    int c4   = (tid & 15) * 4;
    int mloc = tid >> 4;
    const ushort* xb = xT + (size_t)b * Nin * CC + c4;
    #pragma unroll
    for (int pass = 0; pass < 4; ++pass) {
        int ml = mloc + pass * 16;
        int m  = m0 + ml;
        const int* ip = idx + ((size_t)b * NSUB + m) * KNN;
        float a0 = -1e30f, a1 = -1e30f, a2 = -1e30f, a3 = -1e30f;
        #pragma unroll
        for (int k = 0; k < KNN; ++k) {
            int j = ip[k];
            ushort4 v = *(const ushort4*)(xb + (size_t)j * CC);
            a0 = fmaxf(a0, bf2f(v.x));
            a1 = fmaxf(a1, bf2f(v.y));
            a2 = fmaxf(a2, bf2f(v.z));
            a3 = fmaxf(a3, bf2f(v.w));
        }
        ushort4 r;
        r.x = f2bf(a0); r.y = f2bf(a1); r.z = f2bf(a2); r.w = f2bf(a3);
        *(ushort4*)(&sm[ml * 72 + c4]) = r;
        if (pt)   // maxpool output reused by phase-3 point-path
            *(ushort4*)(p.pe0T + ((size_t)b * NSUB + m) * CC + c4) = r;
    }
    __syncthreads();
    // pre-conv GEMM: D = Xtile(A rows=n from LDS) * W^T(B cols=o), K=64
    int wave = tid >> 6, lane = tid & 63;
    int l15 = lane & 15, quad = lane >> 4;
    int nloc0 = wave * 16;
    floatx4 acc[4] = {{0.f,0.f,0.f,0.f},{0.f,0.f,0.f,0.f},{0.f,0.f,0.f,0.f},{0.f,0.f,0.f,0.f}};
    #pragma unroll
    for (int kk = 0; kk < 2; ++kk) {
        short8 a = *(const short8*)(&sm[(nloc0 + l15) * 72 + kk * 32 + quad * 8]);
        #pragma unroll
        for (int t = 0; t < 4; ++t) {
            short8 wf = *(const short8*)(W + (size_t)(t * 16 + l15) * CC + kk * 32 + quad * 8);
            acc[t] = __builtin_amdgcn_mfma_f32_16x16x32_bf16(a, wf, acc[t], 0, 0, 0);
        }
    }
    #pragma unroll
    for (int t = 0; t < 4; ++t) {
        int o = t * 16 + l15;
        float ss = sv[o], bb2 = bv[o];
        #pragma unroll
        for (int r = 0; r < 4; ++r) {
            int n = m0 + nloc0 + quad * 4 + r;
            float y = fmaxf(acc[t][r] * ss + bb2, 0.f);
            dst[((size_t)b * NSUB + n) * CC + o] = f2bf(y);
        }
    }
}

// ---------------------------------------------------------------------------
// K3: both fuse GEMMs -> d_out. grid 2800: w<2400 rgb-path, else point-path.
// D = W(A rows=o) * X(B cols=n), K=128.
// ---------------------------------------------------------------------------
__global__ __launch_bounds__(256) void k_p3(P p) {
    int w = blockIdx.x, tid = threadIdx.x;
    bool rp = (w < 2400);
    int v0 = rp ? w : w - 2400;
    int b = v0 & 7, x0 = v0 >> 3;     // 0..299 / 0..49
    const ushort* x1T = rp ? p.rgbT : p.pe0T;
    const ushort* x2T = rp ? p.p2rT : p.r2pT;
    int N             = rp ? HWN : NSUB;
    int pos0          = rp ? 0 : HWN;
    const ushort* W   = rp ? p.wB + 8192 : p.wB + 16384;   // [64][128]
    const float*  sv  = rp ? p.s_pf : p.s_rf;
    const float*  bv  = rp ? p.b_pf : p.b_rf;

    int wave = tid >> 6, lane = tid & 63;
    int n0 = (x0 * 4 + wave) * 16;
    int l15 = lane & 15, quad = lane >> 4;
    int n  = n0 + l15;
    int n2 = rp ? p.p2r_idx[(size_t)b * N + n] : n;
    const ushort* r1 = x1T + ((size_t)b * N + n) * CC + quad * 8;
    const ushort* r2 = x2T + ((size_t)b * NSUB + n2) * CC + quad * 8;
    floatx4 acc[4] = {{0.f,0.f,0.f,0.f},{0.f,0.f,0.f,0.f},{0.f,0.f,0.f,0.f},{0.f,0.f,0.f,0.f}};
    #pragma unroll
    for (int kk = 0; kk < 4; ++kk) {
        short8 xb = (kk < 2) ? *(const short8*)(r1 + kk * 32)
                             : *(const short8*)(r2 + (kk - 2) * 32);
        #pragma unroll
        for (int t = 0; t < 4; ++t) {
            short8 wf = *(const short8*)(W + (size_t)(t * 16 + l15) * 128 + kk * 32 + quad * 8);
            acc[t] = __builtin_amdgcn_mfma_f32_16x16x32_bf16(wf, xb, acc[t], 0, 0, 0);
        }
    }
    #pragma unroll
    for (int t = 0; t < 4; ++t) {
        #pragma unroll
        for (int r = 0; r < 4; ++r) {
            int o = t * 16 + quad * 4 + r;
            float y = fmaxf(acc[t][r] * sv[o] + bv[o], 0.f);
            p.out[((size_t)b * CC + o) * OUTN + pos0 + n] = y;
        }
    }
}

extern "C" void kernel_launch(void* const* d_in, const int* in_sizes, int n_in,
                              void* d_out, int out_size, void* d_ws, size_t ws_size,
                              hipStream_t stream) {
    char* ws = (char*)d_ws;
    ushort* wB   = (ushort*)ws; ws += 24576 * 2;
    ushort* pfT  = (ushort*)ws; ws += (size_t)BB * NPTS * CC * 2;
    ushort* rgbT = (ushort*)ws; ws += (size_t)BB * HWN  * CC * 2;
    ushort* pe0T = (ushort*)ws; ws += (size_t)BB * NSUB * CC * 2;
    ushort* p2rT = (ushort*)ws; ws += (size_t)BB * NSUB * CC * 2;
    ushort* r2pT = (ushort*)ws; ws += (size_t)BB * NSUB * CC * 2;

    P p;
    p.pfeat = (const float*)d_in[1];
    p.rgb   = (const float*)d_in[0];
    p.w0    = (const float*)d_in[2];
    p.w1    = (const float*)d_in[8];
    p.w2    = (const float*)d_in[5];
    p.w3    = (const float*)d_in[11];
    p.s_pp  = (const float*)d_in[3];   p.b_pp = (const float*)d_in[4];
    p.s_rp  = (const float*)d_in[9];   p.b_rp = (const float*)d_in[10];
    p.s_pf  = (const float*)d_in[6];   p.b_pf = (const float*)d_in[7];
    p.s_rf  = (const float*)d_in[12];  p.b_rf = (const float*)d_in[13];
    p.pool_idx = (const int*)d_in[14];
    p.p2r_idx  = (const int*)d_in[15];
    p.r2p_idx  = (const int*)d_in[16];
    p.wB = wB; p.pfT = pfT; p.rgbT = rgbT;
    p.pe0T = pe0T; p.p2rT = p2rT; p.r2pT = r2pT;
    p.out = (float*)d_out;

    k_p1<<<dim3(4096), 256, 0, stream>>>(p);
    k_p2<<<dim3(800),  256, 0, stream>>>(p);
    k_p3<<<dim3(2800), 256, 0, stream>>>(p);
}

// Round 7
// 172.510 us; speedup vs baseline: 2.1815x; 1.1352x over previous
//
#include <hip/hip_runtime.h>

#define BB   8
#define CC   64
#define HWN  19200
#define NPTS 12800
#define NSUB 3200
#define KNN  16
#define OUTN (HWN + NSUB)   // 22400

typedef __attribute__((ext_vector_type(8))) short short8;
typedef __attribute__((ext_vector_type(4))) float floatx4;

__device__ __forceinline__ unsigned short f2bf(float f) {
    union { float f; unsigned int i; } v; v.f = f;
    unsigned int r = v.i + 0x7fffu + ((v.i >> 16) & 1u);
    return (unsigned short)(r >> 16);
}
__device__ __forceinline__ float bf2f(unsigned short u) {
    union { unsigned int i; float f; } v; v.i = ((unsigned int)u) << 16; return v.f;
}

struct P {
    const float* pfeat; const float* rgb;
    const float* w0; const float* w1; const float* w2; const float* w3;
    const float* s_pp; const float* b_pp;
    const float* s_rp; const float* b_rp;
    const float* s_pf; const float* b_pf;
    const float* s_rf; const float* b_rf;
    const int* pool_idx; const int* p2r_idx; const int* r2p_idx;
    ushort* wB; ushort* pfT; ushort* rgbT;
    ushort* pe0T; ushort* p2rT; ushort* r2pT;
    float* out;
};

// ---------------------------------------------------------------------------
// K1: transposes f32 [B][C][N] -> bf16 [B][N][C] (float4 in, ushort4 out)
// + weight conversion. grid 4096: w<1600 pfeat, <4000 rgb, >=4000 weights.
// ---------------------------------------------------------------------------
__global__ __launch_bounds__(256) void k_p1(P p) {
    __shared__ ushort sm[64 * 65];
    int w = blockIdx.x, tid = threadIdx.x;
    if (w >= 4000) {              // weight cvt: 96 blocks x 256 = 24576 elems
        int i = (w - 4000) * 256 + tid;
        float v;
        if (i < 4096)       v = p.w0[i];
        else if (i < 8192)  v = p.w1[i - 4096];
        else if (i < 16384) v = p.w2[i - 8192];
        else                v = p.w3[i - 16384];
        p.wB[i] = f2bf(v);
        return;
    }
    bool isR = (w >= 1600);
    int v0 = isR ? w - 1600 : w;
    int b = v0 & 7, xx = v0 >> 3;
    const float* src = (isR ? p.rgb : p.pfeat);
    ushort* outp     = (isR ? p.rgbT : p.pfT);
    int N  = isR ? HWN : NPTS;
    int n0 = xx * 64;
    src += (size_t)b * CC * N + n0;

    int l = tid & 15, ch = tid >> 4;
    #pragma unroll
    for (int it = 0; it < 4; ++it) {
        int c = ch + 16 * it;
        float4 v = *(const float4*)(src + (size_t)c * N + 4 * l);
        sm[c * 65 + 4 * l + 0] = f2bf(v.x);
        sm[c * 65 + 4 * l + 1] = f2bf(v.y);
        sm[c * 65 + 4 * l + 2] = f2bf(v.z);
        sm[c * 65 + 4 * l + 3] = f2bf(v.w);
    }
    __syncthreads();
    ushort* dst = outp + ((size_t)b * N + n0) * CC;
    int c4 = (tid & 15) * 4;
    #pragma unroll
    for (int it = 0; it < 4; ++it) {
        int n = (tid >> 4) + 16 * it;
        ushort4 r;
        r.x = sm[(c4 + 0) * 65 + n];
        r.y = sm[(c4 + 1) * 65 + n];
        r.z = sm[(c4 + 2) * 65 + n];
        r.w = sm[(c4 + 3) * 65 + n];
        *(ushort4*)(dst + (size_t)n * CC + c4) = r;
    }
}

// ---------------------------------------------------------------------------
// K2: gather + maxpool + pre-conv GEMM. grid 800: w<400 point-stream,
// else rgb-stream. One block = 64 points.
// ---------------------------------------------------------------------------
__global__ __launch_bounds__(256) void k_p2(P p) {
    __shared__ ushort sm[64 * 72];
    int w = blockIdx.x, tid = threadIdx.x;
    bool pt = (w < 400);
    int v0 = pt ? w : w - 400;
    int b = v0 & 7, xx = v0 >> 3;     // xx 0..49
    int m0 = xx * 64;
    const ushort* xT  = pt ? p.pfT : p.rgbT;
    const int*    idx = pt ? p.pool_idx : p.r2p_idx;
    int Nin           = pt ? NPTS : HWN;
    const ushort* W   = pt ? p.wB : p.wB + 4096;   // [64][64]
    const float*  sv  = pt ? p.s_pp : p.s_rp;
    const float*  bv  = pt ? p.b_pp : p.b_rp;
    ushort*       dst = pt ? p.p2rT : p.r2pT;

    int c4   = (tid & 15) * 4;
    int mloc = tid >> 4;
    const ushort* xb = xT + (size_t)b * Nin * CC + c4;
    #pragma unroll
    for (int pass = 0; pass < 4; ++pass) {
        int ml = mloc + pass * 16;
        int m  = m0 + ml;
        const int4* ip4 = (const int4*)(idx + ((size_t)b * NSUB + m) * KNN);
        float a0 = -1e30f, a1 = -1e30f, a2 = -1e30f, a3 = -1e30f;
        #pragma unroll
        for (int k4 = 0; k4 < 4; ++k4) {
            int4 q = ip4[k4];
            int js[4] = { q.x, q.y, q.z, q.w };
            #pragma unroll
            for (int u = 0; u < 4; ++u) {
                ushort4 v = *(const ushort4*)(xb + (size_t)js[u] * CC);
                a0 = fmaxf(a0, bf2f(v.x));
                a1 = fmaxf(a1, bf2f(v.y));
                a2 = fmaxf(a2, bf2f(v.z));
                a3 = fmaxf(a3, bf2f(v.w));
            }
        }
        ushort4 r;
        r.x = f2bf(a0); r.y = f2bf(a1); r.z = f2bf(a2); r.w = f2bf(a3);
        *(ushort4*)(&sm[ml * 72 + c4]) = r;
        if (pt)   // maxpool output reused by k_p3 point-path
            *(ushort4*)(p.pe0T + ((size_t)b * NSUB + m) * CC + c4) = r;
    }
    __syncthreads();
    // pre-conv GEMM: D = Xtile(A rows=n from LDS) * W^T(B cols=o), K=64
    int wave = tid >> 6, lane = tid & 63;
    int l15 = lane & 15, quad = lane >> 4;
    int nloc0 = wave * 16;
    floatx4 acc[4] = {{0.f,0.f,0.f,0.f},{0.f,0.f,0.f,0.f},{0.f,0.f,0.f,0.f},{0.f,0.f,0.f,0.f}};
    #pragma unroll
    for (int kk = 0; kk < 2; ++kk) {
        short8 a = *(const short8*)(&sm[(nloc0 + l15) * 72 + kk * 32 + quad * 8]);
        #pragma unroll
        for (int t = 0; t < 4; ++t) {
            short8 wf = *(const short8*)(W + (size_t)(t * 16 + l15) * CC + kk * 32 + quad * 8);
            acc[t] = __builtin_amdgcn_mfma_f32_16x16x32_bf16(a, wf, acc[t], 0, 0, 0);
        }
    }
    #pragma unroll
    for (int t = 0; t < 4; ++t) {
        int o = t * 16 + l15;
        float ss = sv[o], bb2 = bv[o];
        #pragma unroll
        for (int r = 0; r < 4; ++r) {
            int n = m0 + nloc0 + quad * 4 + r;
            float y = fmaxf(acc[t][r] * ss + bb2, 0.f);
            dst[((size_t)b * NSUB + n) * CC + o] = f2bf(y);
        }
    }
}

// ---------------------------------------------------------------------------
// K3: both fuse GEMMs -> d_out.  D = W(A rows=o) * X(B cols=n), K=128.
// Each wave: 64 cols as 4 interleaved 16-col tiles (tile g owns cols
// l15*4+g) so each lane owns 4 CONSECUTIVE n -> dwordx4 stores.
// grid 704: w<600 rgb-path (75 x0 * 8 b, 256 cols/block);
//           w>=600 point-path (13 x0 * 8 b, guarded at n>=3200).
// ---------------------------------------------------------------------------
__global__ __launch_bounds__(256) void k_p3(P p) {
    int w = blockIdx.x, tid = threadIdx.x;
    bool rp = (w < 600);
    int v0 = rp ? w : w - 600;
    int b = v0 & 7, x0 = v0 >> 3;     // rgb 0..74 / pt 0..12
    const ushort* x1T = rp ? p.rgbT : p.pe0T;
    const ushort* x2T = rp ? p.p2rT : p.r2pT;
    int N             = rp ? HWN : NSUB;
    int pos0          = rp ? 0 : HWN;
    const ushort* W   = rp ? p.wB + 8192 : p.wB + 16384;   // [64][128]
    const float*  sv  = rp ? p.s_pf : p.s_rf;
    const float*  bv  = rp ? p.b_pf : p.b_rf;

    int wave = tid >> 6, lane = tid & 63;
    int l15 = lane & 15, quad = lane >> 4;
    int n_base = x0 * 256 + wave * 64;
    int ncol   = n_base + l15 * 4;          // lane's 4 consecutive cols
    bool act   = rp || (ncol < NSUB);       // uniform over the lane's 4 cols
    int nc     = act ? ncol : 0;

    // row pointers per tile g (col n = nc + g)
    const ushort* r1[4];
    const ushort* r2[4];
    if (rp) {
        int4 i4 = *(const int4*)(p.p2r_idx + (size_t)b * N + nc);
        int n2s[4] = { i4.x, i4.y, i4.z, i4.w };
        #pragma unroll
        for (int g = 0; g < 4; ++g) {
            r1[g] = x1T + ((size_t)b * N + nc + g) * CC + quad * 8;
            r2[g] = x2T + ((size_t)b * NSUB + n2s[g]) * CC + quad * 8;
        }
    } else {
        #pragma unroll
        for (int g = 0; g < 4; ++g) {
            r1[g] = x1T + ((size_t)b * N + nc + g) * CC + quad * 8;
            r2[g] = x2T + ((size_t)b * NSUB + nc + g) * CC + quad * 8;
        }
    }

    floatx4 acc[4][4];   // [g][t]
    #pragma unroll
    for (int g = 0; g < 4; ++g)
        #pragma unroll
        for (int t = 0; t < 4; ++t)
            acc[g][t] = floatx4{0.f, 0.f, 0.f, 0.f};

    #pragma unroll
    for (int kk = 0; kk < 4; ++kk) {
        short8 xf[4];
        #pragma unroll
        for (int g = 0; g < 4; ++g)
            xf[g] = (kk < 2) ? *(const short8*)(r1[g] + kk * 32)
                             : *(const short8*)(r2[g] + (kk - 2) * 32);
        #pragma unroll
        for (int t = 0; t < 4; ++t) {
            short8 wf = *(const short8*)(W + (size_t)(t * 16 + l15) * 128 + kk * 32 + quad * 8);
            #pragma unroll
            for (int g = 0; g < 4; ++g)
                acc[g][t] = __builtin_amdgcn_mfma_f32_16x16x32_bf16(wf, xf[g], acc[g][t], 0, 0, 0);
        }
    }

    // epilogue: 16 dwordx4 stores (256B contiguous per quad-row)
    #pragma unroll
    for (int t = 0; t < 4; ++t) {
        #pragma unroll
        for (int r = 0; r < 4; ++r) {
            int o = t * 16 + quad * 4 + r;
            float ss = sv[o], bb2 = bv[o];
            float4 y;
            y.x = fmaxf(acc[0][t][r] * ss + bb2, 0.f);
            y.y = fmaxf(acc[1][t][r] * ss + bb2, 0.f);
            y.z = fmaxf(acc[2][t][r] * ss + bb2, 0.f);
            y.w = fmaxf(acc[3][t][r] * ss + bb2, 0.f);
            if (act)
                *(float4*)(p.out + ((size_t)b * CC + o) * OUTN + pos0 + nc) = y;
        }
    }
}

extern "C" void kernel_launch(void* const* d_in, const int* in_sizes, int n_in,
                              void* d_out, int out_size, void* d_ws, size_t ws_size,
                              hipStream_t stream) {
    char* ws = (char*)d_ws;
    ushort* wB   = (ushort*)ws; ws += 24576 * 2;
    ushort* pfT  = (ushort*)ws; ws += (size_t)BB * NPTS * CC * 2;
    ushort* rgbT = (ushort*)ws; ws += (size_t)BB * HWN  * CC * 2;
    ushort* pe0T = (ushort*)ws; ws += (size_t)BB * NSUB * CC * 2;
    ushort* p2rT = (ushort*)ws; ws += (size_t)BB * NSUB * CC * 2;
    ushort* r2pT = (ushort*)ws; ws += (size_t)BB * NSUB * CC * 2;

    P p;
    p.pfeat = (const float*)d_in[1];
    p.rgb   = (const float*)d_in[0];
    p.w0    = (const float*)d_in[2];
    p.w1    = (const float*)d_in[8];
    p.w2    = (const float*)d_in[5];
    p.w3    = (const float*)d_in[11];
    p.s_pp  = (const float*)d_in[3];   p.b_pp = (const float*)d_in[4];
    p.s_rp  = (const float*)d_in[9];   p.b_rp = (const float*)d_in[10];
    p.s_pf  = (const float*)d_in[6];   p.b_pf = (const float*)d_in[7];
    p.s_rf  = (const float*)d_in[12];  p.b_rf = (const float*)d_in[13];
    p.pool_idx = (const int*)d_in[14];
    p.p2r_idx  = (const int*)d_in[15];
    p.r2p_idx  = (const int*)d_in[16];
    p.wB = wB; p.pfT = pfT; p.rgbT = rgbT;
    p.pe0T = pe0T; p.p2rT = p2rT; p.r2pT = r2pT;
    p.out = (float*)d_out;

    k_p1<<<dim3(4096), 256, 0, stream>>>(p);
    k_p2<<<dim3(800),  256, 0, stream>>>(p);
    k_p3<<<dim3(704),  256, 0, stream>>>(p);
}

// Round 8
// 172.147 us; speedup vs baseline: 2.1861x; 1.0021x over previous
//
#include <hip/hip_runtime.h>

#define BB   8
#define CC   64
#define HWN  19200
#define NPTS 12800
#define NSUB 3200
#define KNN  16
#define OUTN (HWN + NSUB)   // 22400

typedef __attribute__((ext_vector_type(8))) short short8;
typedef __attribute__((ext_vector_type(4))) float floatx4;

__device__ __forceinline__ unsigned short f2bf(float f) {
    union { float f; unsigned int i; } v; v.f = f;
    unsigned int r = v.i + 0x7fffu + ((v.i >> 16) & 1u);
    return (unsigned short)(r >> 16);
}
__device__ __forceinline__ float bf2f(unsigned short u) {
    union { unsigned int i; float f; } v; v.i = ((unsigned int)u) << 16; return v.f;
}

struct P {
    const float* pfeat; const float* rgb;
    const float* w0; const float* w1; const float* w2; const float* w3;
    const float* s_pp; const float* b_pp;
    const float* s_rp; const float* b_rp;
    const float* s_pf; const float* b_pf;
    const float* s_rf; const float* b_rf;
    const int* pool_idx; const int* p2r_idx; const int* r2p_idx;
    ushort* wB; ushort* pfT; ushort* rgbT;
    ushort* pe0T; ushort* p2rT; ushort* r2pT;
    float* out;
};

// ---------------------------------------------------------------------------
// K1: transpose f32 [B][C][N] -> bf16 [B][N][C], 128 n-cols (2 tiles) per
// block, all loads in flight before one sync. grid 2096:
//   w<800 pfeat (100 x 8), w<2000 rgb (150 x 8), w>=2000 weights (96).
// ---------------------------------------------------------------------------
__global__ __launch_bounds__(256) void k_p1(P p) {
    __shared__ ushort sm[2][64 * 65];
    int w = blockIdx.x, tid = threadIdx.x;
    if (w >= 2000) {              // weight cvt: 96 blocks x 256 = 24576 elems
        int i = (w - 2000) * 256 + tid;
        float v;
        if (i < 4096)       v = p.w0[i];
        else if (i < 8192)  v = p.w1[i - 4096];
        else if (i < 16384) v = p.w2[i - 8192];
        else                v = p.w3[i - 16384];
        p.wB[i] = f2bf(v);
        return;
    }
    bool isR = (w >= 800);
    int v0 = isR ? w - 800 : w;
    int b = v0 & 7, xx = v0 >> 3;          // pf 0..99 / rgb 0..149
    const float* src = (isR ? p.rgb : p.pfeat);
    ushort* outp     = (isR ? p.rgbT : p.pfT);
    int N  = isR ? HWN : NPTS;
    int n0 = xx * 128;
    src += (size_t)b * CC * N + n0;

    int l = tid & 15, ch = tid >> 4;
    // issue all 8 float4 loads (2 tiles x 4 c-rows) before any use
    float4 v[2][4];
    #pragma unroll
    for (int s = 0; s < 2; ++s)
        #pragma unroll
        for (int it = 0; it < 4; ++it)
            v[s][it] = *(const float4*)(src + (size_t)(ch + 16 * it) * N + s * 64 + 4 * l);
    #pragma unroll
    for (int s = 0; s < 2; ++s)
        #pragma unroll
        for (int it = 0; it < 4; ++it) {
            int c = ch + 16 * it;
            sm[s][c * 65 + 4 * l + 0] = f2bf(v[s][it].x);
            sm[s][c * 65 + 4 * l + 1] = f2bf(v[s][it].y);
            sm[s][c * 65 + 4 * l + 2] = f2bf(v[s][it].z);
            sm[s][c * 65 + 4 * l + 3] = f2bf(v[s][it].w);
        }
    __syncthreads();
    ushort* dst = outp + ((size_t)b * N + n0) * CC;
    int c4 = (tid & 15) * 4;
    #pragma unroll
    for (int s = 0; s < 2; ++s)
        #pragma unroll
        for (int it = 0; it < 4; ++it) {
            int n = (tid >> 4) + 16 * it;
            ushort4 r;
            r.x = sm[s][(c4 + 0) * 65 + n];
            r.y = sm[s][(c4 + 1) * 65 + n];
            r.z = sm[s][(c4 + 2) * 65 + n];
            r.w = sm[s][(c4 + 3) * 65 + n];
            *(ushort4*)(dst + (size_t)(s * 64 + n) * CC + c4) = r;
        }
}

// ---------------------------------------------------------------------------
// K2: gather + maxpool + pre-conv GEMM. grid 800: w<400 point-stream,
// else rgb-stream. One block = 64 points. Gather lanes are 16B-wide
// (ushort8, 8 lanes/point, 32 points/pass, 2 passes).
// ---------------------------------------------------------------------------
__global__ __launch_bounds__(256) void k_p2(P p) {
    __shared__ ushort sm[64 * 72];
    int w = blockIdx.x, tid = threadIdx.x;
    bool pt = (w < 400);
    int v0 = pt ? w : w - 400;
    int b = v0 & 7, xx = v0 >> 3;     // xx 0..49
    int m0 = xx * 64;
    const ushort* xT  = pt ? p.pfT : p.rgbT;
    const int*    idx = pt ? p.pool_idx : p.r2p_idx;
    int Nin           = pt ? NPTS : HWN;
    const ushort* W   = pt ? p.wB : p.wB + 4096;   // [64][64]
    const float*  sv  = pt ? p.s_pp : p.s_rp;
    const float*  bv  = pt ? p.b_pp : p.b_rp;
    ushort*       dst = pt ? p.p2rT : p.r2pT;

    int c8   = (tid & 7) * 8;     // 8 channels per lane
    int mloc = tid >> 3;          // 0..31: 32 points per pass
    const ushort* xb = xT + (size_t)b * Nin * CC + c8;
    #pragma unroll
    for (int pass = 0; pass < 2; ++pass) {
        int ml = mloc + pass * 32;
        int m  = m0 + ml;
        const int4* ip4 = (const int4*)(idx + ((size_t)b * NSUB + m) * KNN);
        int4 q0 = ip4[0], q1 = ip4[1], q2 = ip4[2], q3 = ip4[3];
        int js[16] = { q0.x, q0.y, q0.z, q0.w, q1.x, q1.y, q1.z, q1.w,
                       q2.x, q2.y, q2.z, q2.w, q3.x, q3.y, q3.z, q3.w };
        float a[8];
        #pragma unroll
        for (int u = 0; u < 8; ++u) a[u] = -1e30f;
        #pragma unroll
        for (int k = 0; k < KNN; ++k) {
            short8 val = *(const short8*)(xb + (size_t)js[k] * CC);
            #pragma unroll
            for (int u = 0; u < 8; ++u)
                a[u] = fmaxf(a[u], bf2f((unsigned short)val[u]));
        }
        short8 r;
        #pragma unroll
        for (int u = 0; u < 8; ++u) r[u] = (short)f2bf(a[u]);
        *(short8*)(&sm[ml * 72 + c8]) = r;
        if (pt)   // maxpool output reused by k_p3 point-path
            *(short8*)(p.pe0T + ((size_t)b * NSUB + m) * CC + c8) = r;
    }
    __syncthreads();
    // pre-conv GEMM: D = Xtile(A rows=n from LDS) * W^T(B cols=o), K=64
    int wave = tid >> 6, lane = tid & 63;
    int l15 = lane & 15, quad = lane >> 4;
    int nloc0 = wave * 16;
    floatx4 acc[4] = {{0.f,0.f,0.f,0.f},{0.f,0.f,0.f,0.f},{0.f,0.f,0.f,0.f},{0.f,0.f,0.f,0.f}};
    #pragma unroll
    for (int kk = 0; kk < 2; ++kk) {
        short8 a = *(const short8*)(&sm[(nloc0 + l15) * 72 + kk * 32 + quad * 8]);
        #pragma unroll
        for (int t = 0; t < 4; ++t) {
            short8 wf = *(const short8*)(W + (size_t)(t * 16 + l15) * CC + kk * 32 + quad * 8);
            acc[t] = __builtin_amdgcn_mfma_f32_16x16x32_bf16(a, wf, acc[t], 0, 0, 0);
        }
    }
    #pragma unroll
    for (int t = 0; t < 4; ++t) {
        int o = t * 16 + l15;
        float ss = sv[o], bb2 = bv[o];
        #pragma unroll
        for (int r = 0; r < 4; ++r) {
            int n = m0 + nloc0 + quad * 4 + r;
            float y = fmaxf(acc[t][r] * ss + bb2, 0.f);
            dst[((size_t)b * NSUB + n) * CC + o] = f2bf(y);
        }
    }
}

// ---------------------------------------------------------------------------
// K3: both fuse GEMMs -> d_out.  D = W(A rows=o) * X(B cols=n), K=128.
// Each wave: 64 cols as 4 interleaved 16-col tiles; lane owns 4 consecutive
// n -> dwordx4 stores. grid 704: w<600 rgb, else point (guarded).
// ---------------------------------------------------------------------------
__global__ __launch_bounds__(256) void k_p3(P p) {
    int w = blockIdx.x, tid = threadIdx.x;
    bool rp = (w < 600);
    int v0 = rp ? w : w - 600;
    int b = v0 & 7, x0 = v0 >> 3;     // rgb 0..74 / pt 0..12
    const ushort* x1T = rp ? p.rgbT : p.pe0T;
    const ushort* x2T = rp ? p.p2rT : p.r2pT;
    int N             = rp ? HWN : NSUB;
    int pos0          = rp ? 0 : HWN;
    const ushort* W   = rp ? p.wB + 8192 : p.wB + 16384;   // [64][128]
    const float*  sv  = rp ? p.s_pf : p.s_rf;
    const float*  bv  = rp ? p.b_pf : p.b_rf;

    int wave = tid >> 6, lane = tid & 63;
    int l15 = lane & 15, quad = lane >> 4;
    int n_base = x0 * 256 + wave * 64;
    int ncol   = n_base + l15 * 4;
    bool act   = rp || (ncol < NSUB);
    int nc     = act ? ncol : 0;

    const ushort* r1[4];
    const ushort* r2[4];
    if (rp) {
        int4 i4 = *(const int4*)(p.p2r_idx + (size_t)b * N + nc);
        int n2s[4] = { i4.x, i4.y, i4.z, i4.w };
        #pragma unroll
        for (int g = 0; g < 4; ++g) {
            r1[g] = x1T + ((size_t)b * N + nc + g) * CC + quad * 8;
            r2[g] = x2T + ((size_t)b * NSUB + n2s[g]) * CC + quad * 8;
        }
    } else {
        #pragma unroll
        for (int g = 0; g < 4; ++g) {
            r1[g] = x1T + ((size_t)b * N + nc + g) * CC + quad * 8;
            r2[g] = x2T + ((size_t)b * NSUB + nc + g) * CC + quad * 8;
        }
    }

    floatx4 acc[4][4];   // [g][t]
    #pragma unroll
    for (int g = 0; g < 4; ++g)
        #pragma unroll
        for (int t = 0; t < 4; ++t)
            acc[g][t] = floatx4{0.f, 0.f, 0.f, 0.f};

    #pragma unroll
    for (int kk = 0; kk < 4; ++kk) {
        short8 xf[4];
        #pragma unroll
        for (int g = 0; g < 4; ++g)
            xf[g] = (kk < 2) ? *(const short8*)(r1[g] + kk * 32)
                             : *(const short8*)(r2[g] + (kk - 2) * 32);
        #pragma unroll
        for (int t = 0; t < 4; ++t) {
            short8 wf = *(const short8*)(W + (size_t)(t * 16 + l15) * 128 + kk * 32 + quad * 8);
            #pragma unroll
            for (int g = 0; g < 4; ++g)
                acc[g][t] = __builtin_amdgcn_mfma_f32_16x16x32_bf16(wf, xf[g], acc[g][t], 0, 0, 0);
        }
    }

    #pragma unroll
    for (int t = 0; t < 4; ++t) {
        #pragma unroll
        for (int r = 0; r < 4; ++r) {
            int o = t * 16 + quad * 4 + r;
            float ss = sv[o], bb2 = bv[o];
            float4 y;
            y.x = fmaxf(acc[0][t][r] * ss + bb2, 0.f);
            y.y = fmaxf(acc[1][t][r] * ss + bb2, 0.f);
            y.z = fmaxf(acc[2][t][r] * ss + bb2, 0.f);
            y.w = fmaxf(acc[3][t][r] * ss + bb2, 0.f);
            if (act)
                *(float4*)(p.out + ((size_t)b * CC + o) * OUTN + pos0 + nc) = y;
        }
    }
}

extern "C" void kernel_launch(void* const* d_in, const int* in_sizes, int n_in,
                              void* d_out, int out_size, void* d_ws, size_t ws_size,
                              hipStream_t stream) {
    char* ws = (char*)d_ws;
    ushort* wB   = (ushort*)ws; ws += 24576 * 2;
    ushort* pfT  = (ushort*)ws; ws += (size_t)BB * NPTS * CC * 2;
    ushort* rgbT = (ushort*)ws; ws += (size_t)BB * HWN  * CC * 2;
    ushort* pe0T = (ushort*)ws; ws += (size_t)BB * NSUB * CC * 2;
    ushort* p2rT = (ushort*)ws; ws += (size_t)BB * NSUB * CC * 2;
    ushort* r2pT = (ushort*)ws; ws += (size_t)BB * NSUB * CC * 2;

    P p;
    p.pfeat = (const float*)d_in[1];
    p.rgb   = (const float*)d_in[0];
    p.w0    = (const float*)d_in[2];
    p.w1    = (const float*)d_in[8];
    p.w2    = (const float*)d_in[5];
    p.w3    = (const float*)d_in[11];
    p.s_pp  = (const float*)d_in[3];   p.b_pp = (const float*)d_in[4];
    p.s_rp  = (const float*)d_in[9];   p.b_rp = (const float*)d_in[10];
    p.s_pf  = (const float*)d_in[6];   p.b_pf = (const float*)d_in[7];
    p.s_rf  = (const float*)d_in[12];  p.b_rf = (const float*)d_in[13];
    p.pool_idx = (const int*)d_in[14];
    p.p2r_idx  = (const int*)d_in[15];
    p.r2p_idx  = (const int*)d_in[16];
    p.wB = wB; p.pfT = pfT; p.rgbT = rgbT;
    p.pe0T = pe0T; p.p2rT = p2rT; p.r2pT = r2pT;
    p.out = (float*)d_out;

    k_p1<<<dim3(2096), 256, 0, stream>>>(p);
    k_p2<<<dim3(800),  256, 0, stream>>>(p);
    k_p3<<<dim3(704),  256, 0, stream>>>(p);
}